// Round 15
// baseline (163.195 us; speedup 1.0000x reference)
//
#include <hip/hip_runtime.h>
#include <math.h>

#define TLEN 1000
#define NF 256
#define CIN 8
#define CMID 32
#define TK 5
#define TT 120          // outputs per block
#define THA 128         // stage-A time extent
#define T2R 136         // s_t2h rows
#define SLS 72          // (fallback kernel) s_log row stride bytes

// workspace layout (bytes)
#define CSW_OFF  0u          // 32768 * 32B  = 1048576   (cs A-frags, 4 g-variants)
#define CB_OFF   1048576u    // 8192 * 8B    = 65536     (cs bias pairs)
#define FCP_OFF  1114112u    // 96 * 8B      = 768       (fc weights [j][c] f16 quad {fr,-fi,fi,fr})
#define FCB_OFF  1114880u    // 32 * 8B      = 256       (fc bias {bm,bp})
#define TCW_OFF  1115136u    // 163840 * 16B = 2621440   (tc A-frags)
#define TCB_OFF  3736576u    // 4096 * 4B    = 16384     (tc bias)
#define LA_OFF   3752960u    // 16384 * 16B  = 262144    (last A-frags, 4 g-variants)
#define LAB_OFF  4015104u    // 4096 * 4B    = 16384     (last bias)
#define T1_OFF   4031488u    // t1: [f][t<1000][2c+p] f16 = 128000 B/f
#define T1_BATCH 32768000u   // 256 f * 128000 B
#define WS_ONE   36799488u   // T1_OFF + 1 batch  (proven available)
#define WS_ALL   135103488u  // T1_OFF + 4 batches (in use per R9 timing)

typedef _Float16 f16x8 __attribute__((ext_vector_type(8)));
typedef _Float16 f16x4 __attribute__((ext_vector_type(4)));
typedef _Float16 f16x2 __attribute__((ext_vector_type(2)));
typedef float f32x4 __attribute__((ext_vector_type(4)));

union F16Pairs8 { f16x8 v; f16x2 p[4]; };

#if __has_builtin(__builtin_amdgcn_fdot2)
#define FDOT2(a, b, c) __builtin_amdgcn_fdot2((a), (b), (c), false)
#else
#define FDOT2(a, b, c) fmaf((float)(a)[0], (float)(b)[0], fmaf((float)(a)[1], (float)(b)[1], (c)))
#endif

__device__ __forceinline__ float ftanh(float x) {
    float e = __expf(2.0f * x);
    return 1.0f - 2.0f / (e + 1.0f);
}

__device__ __forceinline__ float fatan2(float y, float x) {
    float ax = fabsf(x), ay = fabsf(y);
    float mx = fmaxf(fmaxf(ax, ay), 1e-30f);
    float mn = fminf(ax, ay);
    float a = mn * __builtin_amdgcn_rcpf(mx);
    float s = a * a;
    float r = fmaf(s, fmaf(s, fmaf(s, fmaf(s, fmaf(s, -0.0117212f, 0.05265332f),
                -0.11643287f), 0.19354346f), -0.33262347f), 0.99997726f);
    r *= a;
    if (ay > ax) r = 1.5707964f - r;
    if (x < 0.0f) r = 3.1415927f - r;
    return copysignf(r, y);
}

// ---------------- pre-kernel 1: weight packing ----------------
__global__ __launch_bounds__(256) void mb_pack(
    const float* __restrict__ cswr, const float* __restrict__ cswi,
    const float* __restrict__ csbr, const float* __restrict__ csbi,
    const float* __restrict__ fcwr, const float* __restrict__ fcwi,
    const float* __restrict__ fcbr, const float* __restrict__ fcbi,
    const float* __restrict__ tcwr, const float* __restrict__ tcwi,
    const float* __restrict__ tcbr, const float* __restrict__ tcbi,
    const float* __restrict__ lawr, const float* __restrict__ lawi,
    const float* __restrict__ labr, const float* __restrict__ labi,
    unsigned char* __restrict__ ws)
{
    int e = blockIdx.x * 256 + threadIdx.x;
    if (e < 32768) {
        int fp = e >> 7, ca = (e >> 2) & 31, g = e & 3;
        f16x8 aRe = (f16x8){0,0,0,0,0,0,0,0}, aIm = (f16x8){0,0,0,0,0,0,0,0};
        if (g < 2) {
            const float* wr = cswr + ((size_t)fp*CMID + ca)*CIN + g*4;
            const float* wi = cswi + ((size_t)fp*CMID + ca)*CIN + g*4;
#pragma unroll
            for (int r = 0; r < 4; ++r) {
                float a = wr[r], bb = wi[r];
                aRe[2*r] = (_Float16)a;  aRe[2*r+1] = (_Float16)(-bb);
                aIm[2*r] = (_Float16)bb; aIm[2*r+1] = (_Float16)a;
            }
        }
        *(f16x8*)(ws + CSW_OFF + (size_t)e*32)      = aRe;
        *(f16x8*)(ws + CSW_OFF + (size_t)e*32 + 16) = aIm;
        return;
    }
    e -= 32768;
    if (e < 8192) {
        int fp = e >> 5, c = e & 31;
        float br = csbr[fp*CMID + c], bi = csbi[fp*CMID + c];
        *(float2*)(ws + CB_OFF + (size_t)e*8) = make_float2(br - bi, br + bi);
        return;
    }
    e -= 8192;
    if (e < 96) {
        // fc weights: [j][c] -> f16 quad {fr, -fi, fi, fr} for fdot2
        int j = e / 32, c = e % 32;
        float fr = fcwr[c*3 + j], fi = fcwi[c*3 + j];
        f16x4 hq = (f16x4){(_Float16)fr, (_Float16)(-fi), (_Float16)fi, (_Float16)fr};
        *(f16x4*)(ws + FCP_OFF + (size_t)e*8) = hq;
        return;
    }
    e -= 96;
    if (e < 32) {
        *(float2*)(ws + FCB_OFF + (size_t)e*8) = make_float2(fcbr[e] - fcbi[e], fcbr[e] + fcbi[e]);
        return;
    }
    e -= 32;
    if (e < 163840) {
        int idx = e % 640;
        int f   = e / 640;
        int m   = idx / 40;
        int r2  = idx % 40;
        int g   = r2 / 10;
        int i10 = r2 % 10;
        int kt = i10 >> 1, kc = i10 & 1;
        int co = m & 7;
        f16x8 v;
#pragma unroll
        for (int j = 0; j < 8; ++j) {
            int ci = kc*16 + g*4 + (j >> 1);
            int p  = j & 1;
            float a  = tcwr[(((size_t)f*CIN + co)*CMID + ci)*TK + kt];
            float bb = tcwi[(((size_t)f*CIN + co)*CMID + ci)*TK + kt];
            float val = (m < 8) ? (p ? -bb : a) : (p ? a : bb);
            v[j] = (_Float16)val;
        }
        *(f16x8*)(ws + TCW_OFF + (size_t)e*16) = v;
        return;
    }
    e -= 163840;
    if (e < 4096) {
        int f = e >> 4, m = e & 15, co = m & 7;
        float br = tcbr[f*CIN + co], bi = tcbi[f*CIN + co];
        *(float*)(ws + TCB_OFF + (size_t)e*4) = (m >= 8) ? (br + bi) : (br - bi);
        return;
    }
    e -= 4096;
    if (e < 16384) {
        int f = e >> 6, m = (e >> 2) & 15, g = e & 3, co = m & 7;
        f16x8 v = (f16x8){0,0,0,0,0,0,0,0};
        if (g < 2) {
#pragma unroll
            for (int j = 0; j < 8; ++j) {
                int ci = g*4 + (j >> 1);
                int p  = j & 1;
                float a  = lawr[((size_t)f*CIN + co)*CIN + ci];
                float bb = lawi[((size_t)f*CIN + co)*CIN + ci];
                float val = (m < 8) ? (p ? -bb : a) : (p ? a : bb);
                v[j] = (_Float16)val;
            }
        }
        *(f16x8*)(ws + LA_OFF + (size_t)e*16) = v;
        return;
    }
    e -= 16384;
    if (e < 4096) {
        int f = e >> 4, m = e & 15, co = m & 7;
        float br = labr[f*CIN + co], bi = labi[f*CIN + co];
        *(float*)(ws + LAB_OFF + (size_t)e*4) = (m >= 8) ? (br + bi) : (br - bi);
    }
}

// ---------------- pre-kernel 2: cLog + cs-mix + cAct -> t1 ----------------
__global__ __launch_bounds__(256, 6) void mb_t1(
    const float* __restrict__ x, unsigned char* __restrict__ ws,
    int b0, unsigned int t1zstride)
{
    const int tid   = threadIdx.x;
    const int chunk = blockIdx.x;     // 0..7 (t chunks of 128)
    const int f     = blockIdx.y;
    const int b     = b0 + blockIdx.z;
    const int t00   = chunk * 128;
    const int lane  = tid & 63;
    const int w     = tid >> 6;
    const int col   = lane & 15;
    const int g     = lane >> 4;

    __shared__ __align__(16) _Float16 sl[128 * 16];   // 4 KB: [t][2ci+p]

    const float* xr_base = x + ((size_t)(b*2+0)*CIN)*NF*TLEN + (size_t)f*TLEN;
    const float* xi_base = x + ((size_t)(b*2+1)*CIN)*NF*TLEN + (size_t)f*TLEN;
#pragma unroll
    for (int it = 0; it < 4; ++it) {
        int i  = it*256 + tid;
        int tl = i & 127, ci = i >> 7;
        int tg = t00 + tl;
        float lr = 0.f, li = 0.f;
        if (tg < TLEN) {
            float vr = xr_base[(size_t)ci*NF*TLEN + tg];
            float vi = xi_base[(size_t)ci*NF*TLEN + tg];
            lr = __logf(sqrtf(fmaf(vr, vr, vi*vi)) + 1e-6f);
            li = fatan2(vi, vr);
        }
        *(f16x2*)&sl[tl*16 + ci*2] = (f16x2){(_Float16)lr, (_Float16)li};
    }
    __syncthreads();

    const f16x8*  cswp = (const f16x8*)(ws + CSW_OFF);
    const float4* cb4  = (const float4*)(ws + CB_OFF);
    const int cBase  = (w & 1) * 16;
    const int ntBase = (w >> 1) * 4;
    const int ca = cBase + col;
    const int cg = cBase + 4*g;
    int abase = (f*128 + ca*4 + g)*2;
    f16x8 aRe = cswp[abase], aIm = cswp[abase + 1];
    int cb0 = f*16 + (cg >> 1);
    float4 c01 = cb4[cb0], c23 = cb4[cb0 + 1];
    float bm[4] = {c01.x, c01.z, c23.x, c23.z};
    float bp[4] = {c01.y, c01.w, c23.y, c23.w};
    unsigned char* t1base = ws + T1_OFF + (size_t)blockIdx.z * t1zstride
                            + (size_t)f * 128000u;
#pragma unroll
    for (int q = 0; q < 4; ++q) {
        int tn = (ntBase + q)*16 + col;
        // (g&1): g>=2 lanes re-read valid finite data (A=0 there); g*8 was the R8 OOB NaN bug
        f16x8 bf = *(const f16x8*)&sl[tn*16 + (g & 1)*8];
        f32x4 dRe = __builtin_amdgcn_mfma_f32_16x16x32_f16(aRe, bf, (f32x4){0,0,0,0}, 0, 0, 0);
        f32x4 dIm = __builtin_amdgcn_mfma_f32_16x16x32_f16(aIm, bf, (f32x4){0,0,0,0}, 0, 0, 0);
        f16x8 v;
#pragma unroll
        for (int r = 0; r < 4; ++r) {
            v[2*r]   = (_Float16)ftanh(dRe[r] + bm[r]);
            v[2*r+1] = (_Float16)fmaxf(dIm[r] + bp[r], 0.f);
        }
        int tg = t00 + tn;
        if (tg < TLEN)
            *(f16x8*)(t1base + (size_t)tg*128u + cg*4) = v;
    }
}

// ---------------- main kernel: fc-combine + tc + cExp + last ----------------
__device__ __forceinline__ int t2r_off(int tl, int kc, int g) {
    int byte = tl * 128 + kc * 64 + g * 16;
    byte ^= (tl & 7) << 4;
    return byte;
}

// R15: R14 (passed, 119.5us) + hoisted FC loads: all 12 t1 loads issue upfront
// (one latency wait instead of three); OOB rows load zeros (dot2 +0 is exact).
__global__ __launch_bounds__(256, 4) void mb_main(
    const unsigned char* __restrict__ ws, float* __restrict__ out,
    int b0, unsigned int t1zstride)
{
    const int tid  = threadIdx.x;
    // XCD-aware swizzle: xcd = d%8 gets contiguous 32-f band (t1 window fits its L2)
    const int d    = blockIdx.x;
    const int f    = (d & 7)*32 + ((d >> 3) & 31);
    const int tb   = d >> 8;
    const int b    = b0 + blockIdx.z;
    const int t0   = tb * TT;
    const int lane = tid & 63;
    const int w    = tid >> 6;
    const int col  = lane & 15;
    const int g    = lane >> 4;

    __shared__ __align__(16) unsigned char s_t2h[T2R * 128];  // 17408 B
    __shared__ __align__(16) float s_y[THA][17];              // 8704 B
    _Float16* s_e = (_Float16*)s_t2h;   // overlay: s_t2h dead after stage C

    // zero tail rows 128..135 (read by stage C, never written by stage B)
    ((unsigned int*)s_t2h)[THA*32 + tid] = 0u;

    const f16x8*  tcp  = (const f16x8*)(ws + TCW_OFF);
    const float4* tb4  = (const float4*)(ws + TCB_OFF);
    const f16x8*  lap  = (const f16x8*)(ws + LA_OFF);
    const float4* lb4  = (const float4*)(ws + LAB_OFF);
    const unsigned char* t1base = ws + T1_OFF + (size_t)blockIdx.z * t1zstride;

    const int cBase  = (w & 1) * 16;
    const int ntBase = (w >> 1) * 4;
    const int cg = cBase + 4*g;

    // per-thread t1 byte offsets (clamped)
    int toff[4];
    {
        int tbv = t0 + ntBase*16 + col;
#pragma unroll
        for (int q = 0; q < 4; ++q) {
            int t = tbv + q*16; if (t > 999) t = 999;
            toff[q] = t*128 + cg*4;
        }
    }

    f32x4 accR[4], accI[4];
#pragma unroll
    for (int q = 0; q < 4; ++q) { accR[q] = (f32x4){0,0,0,0}; accI[q] = (f32x4){0,0,0,0}; }

    // ---- fc freq-conv: ALL 12 t1 loads issued upfront, then dot2 compute ----
    f16x8 hv0[4], hv1[4], hv2[4];
#define FC_LOAD(J, HV)                                                        \
    { const int fp = f - 1 + (J);                                             \
      if (fp >= 0 && fp < NF) {                                               \
        const unsigned char* xb = t1base + (size_t)fp * 128000u;              \
        _Pragma("unroll")                                                     \
        for (int q = 0; q < 4; ++q) HV[q] = *(const f16x8*)(xb + toff[q]);    \
      } else {                                                                \
        _Pragma("unroll")                                                     \
        for (int q = 0; q < 4; ++q) HV[q] = (f16x8){0,0,0,0,0,0,0,0};         \
      } }

    FC_LOAD(0, hv0)
    FC_LOAD(1, hv1)
    FC_LOAD(2, hv2)
#undef FC_LOAD

#define FC_COMP(J, HV)                                                        \
    {                                                                         \
        F16Pairs8 uw01, uw23;                                                 \
        uw01.v = *(const f16x8*)(ws + FCP_OFF + ((J)*32 + cg)*8);             \
        uw23.v = *(const f16x8*)(ws + FCP_OFF + ((J)*32 + cg)*8 + 16);        \
        f16x2 wR[4], wI[4];                                                   \
        wR[0] = uw01.p[0]; wI[0] = uw01.p[1];                                 \
        wR[1] = uw01.p[2]; wI[1] = uw01.p[3];                                 \
        wR[2] = uw23.p[0]; wI[2] = uw23.p[1];                                 \
        wR[3] = uw23.p[2]; wI[3] = uw23.p[3];                                 \
        _Pragma("unroll")                                                     \
        for (int q = 0; q < 4; ++q) {                                         \
            F16Pairs8 uh;                                                     \
            uh.v = HV[q];                                                     \
            _Pragma("unroll")                                                 \
            for (int r = 0; r < 4; ++r) {                                     \
                f16x2 hp = uh.p[r];                                           \
                accR[q][r] = FDOT2(hp, wR[r], accR[q][r]);                    \
                accI[q][r] = FDOT2(hp, wI[r], accI[q][r]);                    \
            }                                                                 \
        } }

    FC_COMP(0, hv0)
    FC_COMP(1, hv1)
    FC_COMP(2, hv2)
#undef FC_COMP

    // ---- stage B: fc bias + act -> s_t2h, one b128 write per q ----
    {
        float4 fb01 = *(const float4*)(ws + FCB_OFF + cg*8);
        float4 fb23 = *(const float4*)(ws + FCB_OFF + cg*8 + 16);
        float fbm[4] = {fb01.x, fb01.z, fb23.x, fb23.z};
        float fbp[4] = {fb01.y, fb01.w, fb23.y, fb23.w};
#pragma unroll
        for (int q = 0; q < 4; ++q) {
            int tp = ntBase*16 + q*16 + col;
            bool pad = (t0 + tp >= TLEN);
            f16x8 v;
#pragma unroll
            for (int r = 0; r < 4; ++r) {
                float tr = ftanh(accR[q][r] + fbm[r]);
                float ti = fmaxf(accI[q][r] + fbp[r], 0.f);
                v[2*r]   = (_Float16)tr;
                v[2*r+1] = (_Float16)ti;
            }
            if (pad) v = (f16x8){0,0,0,0,0,0,0,0};
            int addr = (tp*128 + cg*4) ^ ((tp & 7) << 4);
            *(f16x8*)&s_t2h[addr] = v;
        }
    }

    // ---- stage C A fragments: 10 x 16B loads ----
    f16x8 afr[10];
    {
        int base = ((f*16 + col)*4 + g)*10;
#pragma unroll
        for (int kk = 0; kk < 10; ++kk) afr[kk] = tcp[base + kk];
    }
    __syncthreads();   // s_t2h ready (incl. zeroed tail rows)

    // ---- stage C (tc) MFMA ----
    {
        const int tb0 = w * 32, tb1 = tb0 + 16;
        f32x4 acc0 = {0,0,0,0}, acc1 = {0,0,0,0};
#pragma unroll
        for (int kt = 0; kt < 5; ++kt) {
#pragma unroll
            for (int kc = 0; kc < 2; ++kc) {
                f16x8 b0 = *(const f16x8*)&s_t2h[t2r_off(tb0 + col + 2*kt, kc, g)];
                f16x8 b1 = *(const f16x8*)&s_t2h[t2r_off(tb1 + col + 2*kt, kc, g)];
                acc0 = __builtin_amdgcn_mfma_f32_16x16x32_f16(afr[kt*2+kc], b0, acc0, 0, 0, 0);
                acc1 = __builtin_amdgcn_mfma_f32_16x16x32_f16(afr[kt*2+kc], b1, acc1, 0, 0, 0);
            }
        }
        float4 tcb = tb4[f*4 + g];
        float tcbv[4] = {tcb.x, tcb.y, tcb.z, tcb.w};
#pragma unroll
        for (int r = 0; r < 4; ++r) {
            int mm = g*4 + r;
            s_y[tb0 + col][mm] = acc0[r] + tcbv[r];
            s_y[tb1 + col][mm] = acc1[r] + tcbv[r];
        }
    }
    __syncthreads();   // s_y ready; s_t2h reads done -> s_e overlay usable

    // ---- act + cExp -> s_e (f16 [t][2co+p], overlays s_t2h) ----
#pragma unroll
    for (int it = 0; it < 4; ++it) {
        int i  = it*256 + tid;
        int co = i >> 7, tl = i & 127;
        float yR = s_y[tl][co];
        float yI = s_y[tl][co + 8];
        float mg = __expf(ftanh(yR));
        float ph = fmaxf(yI, 0.f);
        float sn, cs;
        __sincosf(ph, &sn, &cs);
        *(f16x2*)&s_e[tl*16 + co*2] = (f16x2){(_Float16)(mg * cs), (_Float16)(mg * sn)};
    }
    __syncthreads();

    // ---- stage D (last) via MFMA ----
    {
        f16x8 dA = lap[(f*16 + col)*4 + g];
        float4 lb = lb4[f*4 + g];
        float lbv[4] = {lb.x, lb.y, lb.z, lb.w};
        float* obase = out + (size_t)b*4096000 + (size_t)f*TLEN + t0;
        int ooff[4];
#pragma unroll
        for (int r = 0; r < 4; ++r) {
            int m = g*4 + r;
            ooff[r] = (m >> 3)*2048000 + (m & 7)*256000;
        }
#pragma unroll
        for (int t2 = 0; t2 < 2; ++t2) {
            int tp = (w*2 + t2)*16 + col;
            // g>=2 MUST read zeros: junk could be NaN and 0*NaN = NaN in MFMA
            f16x8 eB = (g < 2) ? *(const f16x8*)&s_e[tp*16 + g*8]
                               : (f16x8){0,0,0,0,0,0,0,0};
            f32x4 o = __builtin_amdgcn_mfma_f32_16x16x32_f16(dA, eB, (f32x4){0,0,0,0}, 0, 0, 0);
            if (tp < TT && t0 + tp < TLEN) {
#pragma unroll
                for (int r = 0; r < 4; ++r)
                    obase[ooff[r] + tp] = o[r] + lbv[r];
            }
        }
    }
}

// ---------------- fallback (R7-style fused kernel, used if ws too small) ----------------
__device__ __forceinline__ int t2_off_fb(int tl, int p, int c) {
    int byte = tl * 128 + p * 64 + c * 2;
    byte ^= (tl & 7) << 4;
    return byte >> 1;
}

__global__ __launch_bounds__(256, 4) void mb_fused_fb(
    const float* __restrict__ x,
    const float* __restrict__ cswr, const float* __restrict__ cswi,
    const float* __restrict__ csbr, const float* __restrict__ csbi,
    const float* __restrict__ fcwr, const float* __restrict__ fcwi,
    const float* __restrict__ fcbr, const float* __restrict__ fcbi,
    const float* __restrict__ tcwr, const float* __restrict__ tcwi,
    const float* __restrict__ tcbr, const float* __restrict__ tcbi,
    const float* __restrict__ lawr, const float* __restrict__ lawi,
    const float* __restrict__ labr, const float* __restrict__ labi,
    float* __restrict__ out)
{
    const int tid  = threadIdx.x;
    const int tb   = blockIdx.x;
    const int f    = blockIdx.y;
    const int b    = blockIdx.z;
    const int t0   = tb * TT;
    const int lane = tid & 63;
    const int w    = tid >> 6;
    const int col  = lane & 15;
    const int g    = lane >> 4;

    __shared__ __align__(16) _Float16 s_t2h[T2R * 2 * CMID];
    __shared__ __align__(16) unsigned char s_u[THA * SLS];
    float (*s_y)[17] = (float (*)[17])s_u;

    for (int r = tid; r < THA; r += 256) {
        unsigned int* p = (unsigned int*)(s_u + r * SLS + 32);
        p[0] = 0x00003C00u;
#pragma unroll
        for (int q = 1; q < 8; ++q) p[q] = 0u;
    }
    ((unsigned int*)s_t2h)[THA*32 + tid] = 0u;

    const int cBase  = (w & 1) * 16;
    const int ntBase = (w >> 1) * 4;
    f32x4 accR[4], accI[4];
#pragma unroll
    for (int q = 0; q < 4; ++q) { accR[q] = (f32x4){0,0,0,0}; accI[q] = (f32x4){0,0,0,0}; }

    for (int j = 0; j < 3; ++j) {
        const int fp = f - 1 + j;
        if (fp < 0 || fp >= NF) continue;
        __syncthreads();
        const float* xr_base = x + ((size_t)(b*2+0)*CIN)*NF*TLEN + (size_t)fp*TLEN;
        const float* xi_base = x + ((size_t)(b*2+1)*CIN)*NF*TLEN + (size_t)fp*TLEN;
#pragma unroll
        for (int it = 0; it < 4; ++it) {
            int i  = it*256 + tid;
            int tl = i & 127, ci = i >> 7;
            int tg = t0 + tl;
            float lr = 0.f, li = 0.f;
            if (tg < TLEN) {
                float vr = xr_base[(size_t)ci*NF*TLEN + tg];
                float vi = xi_base[(size_t)ci*NF*TLEN + tg];
                lr = __logf(sqrtf(fmaf(vr, vr, vi*vi)) + 1e-6f);
                li = fatan2(vi, vr);
            }
            *(f16x2*)(s_u + tl*SLS + ci*4) = (f16x2){(_Float16)lr, (_Float16)li};
        }
        __syncthreads();
        const int ca = cBase + col;
        const float4 wrv = *(const float4*)(cswr + ((size_t)fp*CMID + ca)*CIN + (g & 1)*4);
        const float4 wiv = *(const float4*)(cswi + ((size_t)fp*CMID + ca)*CIN + (g & 1)*4);
        const float bR = csbr[fp*CMID + ca], bI = csbi[fp*CMID + ca];
        f16x8 aRe, aIm;
        if (g < 2) {
            aRe = (f16x8){(_Float16)wrv.x, (_Float16)(-wiv.x), (_Float16)wrv.y, (_Float16)(-wiv.y),
                          (_Float16)wrv.z, (_Float16)(-wiv.z), (_Float16)wrv.w, (_Float16)(-wiv.w)};
            aIm = (f16x8){(_Float16)wiv.x, (_Float16)wrv.x, (_Float16)wiv.y, (_Float16)wrv.y,
                          (_Float16)wiv.z, (_Float16)wrv.z, (_Float16)wiv.w, (_Float16)wrv.w};
        } else if (g == 2) {
            aRe = (f16x8){(_Float16)(bR - bI), 0, 0, 0, 0, 0, 0, 0};
            aIm = (f16x8){(_Float16)(bR + bI), 0, 0, 0, 0, 0, 0, 0};
        } else {
            aRe = (f16x8){0,0,0,0,0,0,0,0};
            aIm = (f16x8){0,0,0,0,0,0,0,0};
        }
        float frj[4], fij[4];
#pragma unroll
        for (int r = 0; r < 4; ++r) {
            int c = cBase + g*4 + r;
            frj[r] = fcwr[c*3 + j];
            fij[r] = fcwi[c*3 + j];
        }
#pragma unroll
        for (int q = 0; q < 4; ++q) {
            int tp = (ntBase + q)*16 + col;
            const unsigned char* bp = s_u + tp*SLS + g*16;
            f16x4 blo = *(const f16x4*)bp;
            f16x4 bhi = *(const f16x4*)(bp + 8);
            f16x8 bf = __builtin_shufflevector(blo, bhi, 0, 1, 2, 3, 4, 5, 6, 7);
            f32x4 dRe = __builtin_amdgcn_mfma_f32_16x16x32_f16(aRe, bf, (f32x4){0,0,0,0}, 0, 0, 0);
            f32x4 dIm = __builtin_amdgcn_mfma_f32_16x16x32_f16(aIm, bf, (f32x4){0,0,0,0}, 0, 0, 0);
#pragma unroll
            for (int r = 0; r < 4; ++r) {
                float ar = ftanh(dRe[r]);
                float ai = fmaxf(dIm[r], 0.f);
                accR[q][r] = fmaf(frj[r], ar, fmaf(-fij[r], ai, accR[q][r]));
                accI[q][r] = fmaf(frj[r], ai, fmaf( fij[r], ar, accI[q][r]));
            }
        }
    }
    {
        float fbr[4], fbi[4];
#pragma unroll
        for (int r = 0; r < 4; ++r) {
            int c = cBase + g*4 + r;
            fbr[r] = fcbr[c]; fbi[r] = fcbi[c];
        }
#pragma unroll
        for (int q = 0; q < 4; ++q) {
            int tp = (ntBase + q)*16 + col;
            bool pad = (t0 + tp >= TLEN);
#pragma unroll
            for (int r = 0; r < 4; ++r) {
                int c = cBase + g*4 + r;
                float tr = ftanh(accR[q][r] + (fbr[r] - fbi[r]));
                float ti = fmaxf(accI[q][r] + (fbr[r] + fbi[r]), 0.f);
                if (pad) { tr = 0.f; ti = 0.f; }
                s_t2h[t2_off_fb(tp, 0, c)] = (_Float16)tr;
                s_t2h[t2_off_fb(tp, 1, c)] = (_Float16)ti;
            }
        }
    }
    f16x8 afr[10];
    {
        const bool isI = col >= 8;
        const int co = col & 7;
        const float* wrp = tcwr + (size_t)(f*CIN + co)*(CMID*TK) + g*(8*TK);
        const float* wip = tcwi + (size_t)(f*CIN + co)*(CMID*TK) + g*(8*TK);
#pragma unroll
        for (int q = 0; q < 10; ++q) {
            float4 a4 = *(const float4*)&wrp[q*4];
            float4 b4 = *(const float4*)&wip[q*4];
#pragma unroll
            for (int r = 0; r < 4; ++r) {
                const int idx = q*4 + r;
                const int jj  = idx / 5;
                const int kt  = idx % 5;
                float a  = (r==0)?a4.x:(r==1)?a4.y:(r==2)?a4.z:a4.w;
                float bv = (r==0)?b4.x:(r==1)?b4.y:(r==2)?b4.z:b4.w;
                afr[kt][jj]      = (_Float16)(isI ? bv : a);
                afr[kt + TK][jj] = (_Float16)(isI ? a : -bv);
            }
        }
    }
    __syncthreads();
    {
        const int tb0 = w * 32, tb1 = tb0 + 16;
        f32x4 acc0 = {0,0,0,0}, acc1 = {0,0,0,0};
#pragma unroll
        for (int kk = 0; kk < 10; ++kk) {
            int p  = (kk < 5) ? 0 : 1;
            int kt = (kk < 5) ? kk : kk - 5;
            f16x8 b0 = *(const f16x8*)&s_t2h[t2_off_fb(tb0 + col + 2*kt, p, g*8)];
            f16x8 b1 = *(const f16x8*)&s_t2h[t2_off_fb(tb1 + col + 2*kt, p, g*8)];
            acc0 = __builtin_amdgcn_mfma_f32_16x16x32_f16(afr[kk], b0, acc0, 0, 0, 0);
            acc1 = __builtin_amdgcn_mfma_f32_16x16x32_f16(afr[kk], b1, acc1, 0, 0, 0);
        }
#pragma unroll
        for (int r = 0; r < 4; ++r) {
            int mm = g*4 + r;
            int coo = mm & 7;
            float bRv = tcbr[f*CIN + coo], bIv = tcbi[f*CIN + coo];
            float bias = (mm >= 8) ? (bRv + bIv) : (bRv - bIv);
            s_y[tb0 + col][mm] = acc0[r] + bias;
            s_y[tb1 + col][mm] = acc1[r] + bias;
        }
    }
    __syncthreads();
#pragma unroll
    for (int it = 0; it < 4; ++it) {
        int i  = it*256 + tid;
        int co = i >> 7, tl = i & 127;
        float yR = s_y[tl][co];
        float yI = s_y[tl][co + 8];
        float mg = __expf(ftanh(yR));
        float ph = fmaxf(yI, 0.f);
        float sn, cs;
        __sincosf(ph, &sn, &cs);
        s_y[tl][co]     = mg * cs;
        s_y[tl][co + 8] = mg * sn;
    }
    __syncthreads();
#pragma unroll
    for (int it = 0; it < 4; ++it) {
        int i   = it*256 + tid;
        int tl2 = i & 127;
        int co2 = __builtin_amdgcn_readfirstlane(i >> 7);
        int tg  = t0 + tl2;
        if (tl2 < TT && tg < TLEN) {
            const float4* lr4 = (const float4*)(lawr + ((size_t)f*CIN + co2)*CIN);
            const float4* li4 = (const float4*)(lawi + ((size_t)f*CIN + co2)*CIN);
            float4 a0 = lr4[0], a1 = lr4[1];
            float4 b0 = li4[0], b1 = li4[1];
            float oR = 0.f, oI = 0.f;
#pragma unroll
            for (int co = 0; co < CIN; ++co) {
                float er = s_y[tl2][co];
                float ei = s_y[tl2][co + 8];
                float a  = (co < 4) ? ((co==0)?a0.x:(co==1)?a0.y:(co==2)?a0.z:a0.w)
                                    : ((co==4)?a1.x:(co==5)?a1.y:(co==6)?a1.z:a1.w);
                float bb = (co < 4) ? ((co==0)?b0.x:(co==1)?b0.y:(co==2)?b0.z:b0.w)
                                    : ((co==4)?b1.x:(co==5)?b1.y:(co==6)?b1.z:b1.w);
                oR = fmaf(a, er, fmaf(-bb, ei, oR));
                oI = fmaf(a, ei, fmaf( bb, er, oI));
            }
            float br = labr[f*CIN + co2], bi = labi[f*CIN + co2];
            oR += br - bi;
            oI += br + bi;
            out[((size_t)(b*2+0)*CIN + co2)*NF*TLEN + (size_t)f*TLEN + tg] = oR;
            out[((size_t)(b*2+1)*CIN + co2)*NF*TLEN + (size_t)f*TLEN + tg] = oI;
        }
    }
}

extern "C" void kernel_launch(void* const* d_in, const int* in_sizes, int n_in,
                              void* d_out, int out_size, void* d_ws, size_t ws_size,
                              hipStream_t stream) {
    const float* p[17];
    for (int i = 0; i < 17; ++i) p[i] = (const float*)d_in[i];

    if (ws_size >= WS_ONE) {
        unsigned char* ws = (unsigned char*)d_ws;
        mb_pack<<<dim3(897), 256, 0, stream>>>(
            p[1], p[2], p[3], p[4],
            p[5], p[6], p[7], p[8],
            p[9], p[10], p[11], p[12],
            p[13], p[14], p[15], p[16], ws);
        if (ws_size >= WS_ALL) {
            mb_t1<<<dim3(8, NF, 4), 256, 0, stream>>>(p[0], ws, 0, T1_BATCH);
            mb_main<<<dim3(2304, 1, 4), 256, 0, stream>>>(ws, (float*)d_out, 0, T1_BATCH);
        } else {
            for (int b = 0; b < 4; ++b) {
                mb_t1<<<dim3(8, NF, 1), 256, 0, stream>>>(p[0], ws, b, 0u);
                mb_main<<<dim3(2304, 1, 1), 256, 0, stream>>>(ws, (float*)d_out, b, 0u);
            }
        }
    } else {
        mb_fused_fb<<<dim3(9, NF, 4), 256, 0, stream>>>(
            p[0],
            p[1], p[2], p[3], p[4],
            p[5], p[6], p[7], p[8],
            p[9], p[10], p[11], p[12],
            p[13], p[14], p[15], p[16],
            (float*)d_out);
    }
}

// Round 16
// 161.421 us; speedup vs baseline: 1.0110x; 1.0110x over previous
//
#include <hip/hip_runtime.h>
#include <math.h>

#define TLEN 1000
#define NF 256
#define CIN 8
#define CMID 32
#define TK 5
#define TT 120          // outputs per block
#define THA 128         // stage-A time extent
#define T2R 136         // s_t2h rows
#define SLS 72          // (fallback kernel) s_log row stride bytes
#define SES 24          // s_e row stride in halves (48B: 16B-aligned, 2-way banks)

// workspace layout (bytes)
#define CSW_OFF  0u          // 32768 * 32B  = 1048576   (cs A-frags, 4 g-variants)
#define CB_OFF   1048576u    // 8192 * 8B    = 65536     (cs bias pairs)
#define FCP_OFF  1114112u    // 96 * 8B      = 768       (fc weights [j][c] f16 quad {fr,-fi,fi,fr})
#define FCB_OFF  1114880u    // 32 * 8B      = 256       (fc bias {bm,bp})
#define TCW_OFF  1115136u    // 163840 * 16B = 2621440   (tc A-frags)
#define TCB_OFF  3736576u    // 4096 * 4B    = 16384     (tc bias)
#define LA_OFF   3752960u    // 16384 * 16B  = 262144    (last A-frags, 4 g-variants)
#define LAB_OFF  4015104u    // 4096 * 4B    = 16384     (last bias)
#define T1_OFF   4031488u    // t1: [f][t<1000][2c+p] f16 = 128000 B/f
#define T1_BATCH 32768000u   // 256 f * 128000 B
#define WS_ONE   36799488u   // T1_OFF + 1 batch  (proven available)
#define WS_ALL   135103488u  // T1_OFF + 4 batches (in use per R9 timing)

typedef _Float16 f16x8 __attribute__((ext_vector_type(8)));
typedef _Float16 f16x4 __attribute__((ext_vector_type(4)));
typedef _Float16 f16x2 __attribute__((ext_vector_type(2)));
typedef float f32x4 __attribute__((ext_vector_type(4)));

union F16Pairs8 { f16x8 v; f16x2 p[4]; };

#if __has_builtin(__builtin_amdgcn_fdot2)
#define FDOT2(a, b, c) __builtin_amdgcn_fdot2((a), (b), (c), false)
#else
#define FDOT2(a, b, c) fmaf((float)(a)[0], (float)(b)[0], fmaf((float)(a)[1], (float)(b)[1], (c)))
#endif

__device__ __forceinline__ float ftanh(float x) {
    float e = __expf(2.0f * x);
    return 1.0f - 2.0f / (e + 1.0f);
}

__device__ __forceinline__ float fatan2(float y, float x) {
    float ax = fabsf(x), ay = fabsf(y);
    float mx = fmaxf(fmaxf(ax, ay), 1e-30f);
    float mn = fminf(ax, ay);
    float a = mn * __builtin_amdgcn_rcpf(mx);
    float s = a * a;
    float r = fmaf(s, fmaf(s, fmaf(s, fmaf(s, fmaf(s, -0.0117212f, 0.05265332f),
                -0.11643287f), 0.19354346f), -0.33262347f), 0.99997726f);
    r *= a;
    if (ay > ax) r = 1.5707964f - r;
    if (x < 0.0f) r = 3.1415927f - r;
    return copysignf(r, y);
}

// ---------------- pre-kernel 1: weight packing ----------------
__global__ __launch_bounds__(256) void mb_pack(
    const float* __restrict__ cswr, const float* __restrict__ cswi,
    const float* __restrict__ csbr, const float* __restrict__ csbi,
    const float* __restrict__ fcwr, const float* __restrict__ fcwi,
    const float* __restrict__ fcbr, const float* __restrict__ fcbi,
    const float* __restrict__ tcwr, const float* __restrict__ tcwi,
    const float* __restrict__ tcbr, const float* __restrict__ tcbi,
    const float* __restrict__ lawr, const float* __restrict__ lawi,
    const float* __restrict__ labr, const float* __restrict__ labi,
    unsigned char* __restrict__ ws)
{
    int e = blockIdx.x * 256 + threadIdx.x;
    if (e < 32768) {
        int fp = e >> 7, ca = (e >> 2) & 31, g = e & 3;
        f16x8 aRe = (f16x8){0,0,0,0,0,0,0,0}, aIm = (f16x8){0,0,0,0,0,0,0,0};
        if (g < 2) {
            const float* wr = cswr + ((size_t)fp*CMID + ca)*CIN + g*4;
            const float* wi = cswi + ((size_t)fp*CMID + ca)*CIN + g*4;
#pragma unroll
            for (int r = 0; r < 4; ++r) {
                float a = wr[r], bb = wi[r];
                aRe[2*r] = (_Float16)a;  aRe[2*r+1] = (_Float16)(-bb);
                aIm[2*r] = (_Float16)bb; aIm[2*r+1] = (_Float16)a;
            }
        }
        *(f16x8*)(ws + CSW_OFF + (size_t)e*32)      = aRe;
        *(f16x8*)(ws + CSW_OFF + (size_t)e*32 + 16) = aIm;
        return;
    }
    e -= 32768;
    if (e < 8192) {
        int fp = e >> 5, c = e & 31;
        float br = csbr[fp*CMID + c], bi = csbi[fp*CMID + c];
        *(float2*)(ws + CB_OFF + (size_t)e*8) = make_float2(br - bi, br + bi);
        return;
    }
    e -= 8192;
    if (e < 96) {
        // fc weights: [j][c] -> f16 quad {fr, -fi, fi, fr} for fdot2
        int j = e / 32, c = e % 32;
        float fr = fcwr[c*3 + j], fi = fcwi[c*3 + j];
        f16x4 hq = (f16x4){(_Float16)fr, (_Float16)(-fi), (_Float16)fi, (_Float16)fr};
        *(f16x4*)(ws + FCP_OFF + (size_t)e*8) = hq;
        return;
    }
    e -= 96;
    if (e < 32) {
        *(float2*)(ws + FCB_OFF + (size_t)e*8) = make_float2(fcbr[e] - fcbi[e], fcbr[e] + fcbi[e]);
        return;
    }
    e -= 32;
    if (e < 163840) {
        int idx = e % 640;
        int f   = e / 640;
        int m   = idx / 40;
        int r2  = idx % 40;
        int g   = r2 / 10;
        int i10 = r2 % 10;
        int kt = i10 >> 1, kc = i10 & 1;
        int co = m & 7;
        f16x8 v;
#pragma unroll
        for (int j = 0; j < 8; ++j) {
            int ci = kc*16 + g*4 + (j >> 1);
            int p  = j & 1;
            float a  = tcwr[(((size_t)f*CIN + co)*CMID + ci)*TK + kt];
            float bb = tcwi[(((size_t)f*CIN + co)*CMID + ci)*TK + kt];
            float val = (m < 8) ? (p ? -bb : a) : (p ? a : bb);
            v[j] = (_Float16)val;
        }
        *(f16x8*)(ws + TCW_OFF + (size_t)e*16) = v;
        return;
    }
    e -= 163840;
    if (e < 4096) {
        int f = e >> 4, m = e & 15, co = m & 7;
        float br = tcbr[f*CIN + co], bi = tcbi[f*CIN + co];
        *(float*)(ws + TCB_OFF + (size_t)e*4) = (m >= 8) ? (br + bi) : (br - bi);
        return;
    }
    e -= 4096;
    if (e < 16384) {
        int f = e >> 6, m = (e >> 2) & 15, g = e & 3, co = m & 7;
        f16x8 v = (f16x8){0,0,0,0,0,0,0,0};
        if (g < 2) {
#pragma unroll
            for (int j = 0; j < 8; ++j) {
                int ci = g*4 + (j >> 1);
                int p  = j & 1;
                float a  = lawr[((size_t)f*CIN + co)*CIN + ci];
                float bb = lawi[((size_t)f*CIN + co)*CIN + ci];
                float val = (m < 8) ? (p ? -bb : a) : (p ? a : bb);
                v[j] = (_Float16)val;
            }
        }
        *(f16x8*)(ws + LA_OFF + (size_t)e*16) = v;
        return;
    }
    e -= 16384;
    if (e < 4096) {
        int f = e >> 4, m = e & 15, co = m & 7;
        float br = labr[f*CIN + co], bi = labi[f*CIN + co];
        *(float*)(ws + LAB_OFF + (size_t)e*4) = (m >= 8) ? (br + bi) : (br - bi);
    }
}

// ---------------- pre-kernel 2: cLog + cs-mix + cAct -> t1 ----------------
__global__ __launch_bounds__(256, 6) void mb_t1(
    const float* __restrict__ x, unsigned char* __restrict__ ws,
    int b0, unsigned int t1zstride)
{
    const int tid   = threadIdx.x;
    const int chunk = blockIdx.x;     // 0..7 (t chunks of 128)
    const int f     = blockIdx.y;
    const int b     = b0 + blockIdx.z;
    const int t00   = chunk * 128;
    const int lane  = tid & 63;
    const int w     = tid >> 6;
    const int col   = lane & 15;
    const int g     = lane >> 4;

    __shared__ __align__(16) _Float16 sl[128 * 16];   // 4 KB: [t][2ci+p]

    const float* xr_base = x + ((size_t)(b*2+0)*CIN)*NF*TLEN + (size_t)f*TLEN;
    const float* xi_base = x + ((size_t)(b*2+1)*CIN)*NF*TLEN + (size_t)f*TLEN;
#pragma unroll
    for (int it = 0; it < 4; ++it) {
        int i  = it*256 + tid;
        int tl = i & 127, ci = i >> 7;
        int tg = t00 + tl;
        float lr = 0.f, li = 0.f;
        if (tg < TLEN) {
            float vr = xr_base[(size_t)ci*NF*TLEN + tg];
            float vi = xi_base[(size_t)ci*NF*TLEN + tg];
            lr = __logf(sqrtf(fmaf(vr, vr, vi*vi)) + 1e-6f);
            li = fatan2(vi, vr);
        }
        *(f16x2*)&sl[tl*16 + ci*2] = (f16x2){(_Float16)lr, (_Float16)li};
    }
    __syncthreads();

    const f16x8*  cswp = (const f16x8*)(ws + CSW_OFF);
    const float4* cb4  = (const float4*)(ws + CB_OFF);
    const int cBase  = (w & 1) * 16;
    const int ntBase = (w >> 1) * 4;
    const int ca = cBase + col;
    const int cg = cBase + 4*g;
    int abase = (f*128 + ca*4 + g)*2;
    f16x8 aRe = cswp[abase], aIm = cswp[abase + 1];
    int cb0 = f*16 + (cg >> 1);
    float4 c01 = cb4[cb0], c23 = cb4[cb0 + 1];
    float bm[4] = {c01.x, c01.z, c23.x, c23.z};
    float bp[4] = {c01.y, c01.w, c23.y, c23.w};
    unsigned char* t1base = ws + T1_OFF + (size_t)blockIdx.z * t1zstride
                            + (size_t)f * 128000u;
#pragma unroll
    for (int q = 0; q < 4; ++q) {
        int tn = (ntBase + q)*16 + col;
        // (g&1): g>=2 lanes re-read valid finite data (A=0 there); g*8 was the R8 OOB NaN bug
        f16x8 bf = *(const f16x8*)&sl[tn*16 + (g & 1)*8];
        f32x4 dRe = __builtin_amdgcn_mfma_f32_16x16x32_f16(aRe, bf, (f32x4){0,0,0,0}, 0, 0, 0);
        f32x4 dIm = __builtin_amdgcn_mfma_f32_16x16x32_f16(aIm, bf, (f32x4){0,0,0,0}, 0, 0, 0);
        f16x8 v;
#pragma unroll
        for (int r = 0; r < 4; ++r) {
            v[2*r]   = (_Float16)ftanh(dRe[r] + bm[r]);
            v[2*r+1] = (_Float16)fmaxf(dIm[r] + bp[r], 0.f);
        }
        int tg = t00 + tn;
        if (tg < TLEN)
            *(f16x8*)(t1base + (size_t)tg*128u + cg*4) = v;
    }
}

// ---------------- main kernel: fc-combine + tc + cExp + last ----------------
__device__ __forceinline__ int t2r_off(int tl, int kc, int g) {
    int byte = tl * 128 + kc * 64 + g * 16;
    byte ^= (tl & 7) << 4;
    return byte;
}

// R16: R14 exact (best, 119.5us) + padded s_e stride (16 -> 24 halves / 48B row):
// b128 reads land on 12-bank stride (2-way, free); b32 writes 16-way -> 8-way.
__global__ __launch_bounds__(256, 4) void mb_main(
    const unsigned char* __restrict__ ws, float* __restrict__ out,
    int b0, unsigned int t1zstride)
{
    const int tid  = threadIdx.x;
    // XCD-aware swizzle: xcd = d%8 gets contiguous 32-f band (t1 window fits its L2)
    const int d    = blockIdx.x;
    const int f    = (d & 7)*32 + ((d >> 3) & 31);
    const int tb   = d >> 8;
    const int b    = b0 + blockIdx.z;
    const int t0   = tb * TT;
    const int lane = tid & 63;
    const int w    = tid >> 6;
    const int col  = lane & 15;
    const int g    = lane >> 4;

    __shared__ __align__(16) unsigned char s_t2h[T2R * 128];  // 17408 B
    __shared__ __align__(16) float s_y[THA][17];              // 8704 B
    _Float16* s_e = (_Float16*)s_t2h;   // overlay: s_t2h dead after stage C; 128*SES*2 = 6144 B

    // zero tail rows 128..135 (read by stage C, never written by stage B)
    ((unsigned int*)s_t2h)[THA*32 + tid] = 0u;

    const f16x8*  tcp  = (const f16x8*)(ws + TCW_OFF);
    const float4* tb4  = (const float4*)(ws + TCB_OFF);
    const f16x8*  lap  = (const f16x8*)(ws + LA_OFF);
    const float4* lb4  = (const float4*)(ws + LAB_OFF);
    const unsigned char* t1base = ws + T1_OFF + (size_t)blockIdx.z * t1zstride;

    const int cBase  = (w & 1) * 16;
    const int ntBase = (w >> 1) * 4;
    const int cg = cBase + 4*g;

    // per-thread t1 byte offsets (clamped)
    int toff[4];
    {
        int tbv = t0 + ntBase*16 + col;
#pragma unroll
        for (int q = 0; q < 4; ++q) {
            int t = tbv + q*16; if (t > 999) t = 999;
            toff[q] = t*128 + cg*4;
        }
    }

    f32x4 accR[4], accI[4];
#pragma unroll
    for (int q = 0; q < 4; ++q) { accR[q] = (f32x4){0,0,0,0}; accI[q] = (f32x4){0,0,0,0}; }

    // ---- fc freq-conv via v_dot2_f32_f16 (R14 structure: loads in uniform branches,
    //      compiler hoists; R15's explicit hoist cost VGPR with no gain) ----
#define FC_J(J)                                                               \
    { const int fp = f - 1 + (J);                                             \
      if (fp >= 0 && fp < NF) {                                               \
        const unsigned char* xb = t1base + (size_t)fp * 128000u;              \
        F16Pairs8 uw01, uw23;                                                 \
        uw01.v = *(const f16x8*)(ws + FCP_OFF + ((J)*32 + cg)*8);             \
        uw23.v = *(const f16x8*)(ws + FCP_OFF + ((J)*32 + cg)*8 + 16);        \
        f16x2 wR[4], wI[4];                                                   \
        wR[0] = uw01.p[0]; wI[0] = uw01.p[1];                                 \
        wR[1] = uw01.p[2]; wI[1] = uw01.p[3];                                 \
        wR[2] = uw23.p[0]; wI[2] = uw23.p[1];                                 \
        wR[3] = uw23.p[2]; wI[3] = uw23.p[3];                                 \
        _Pragma("unroll")                                                     \
        for (int q = 0; q < 4; ++q) {                                         \
            F16Pairs8 uh;                                                     \
            uh.v = *(const f16x8*)(xb + toff[q]);                             \
            _Pragma("unroll")                                                 \
            for (int r = 0; r < 4; ++r) {                                     \
                f16x2 hp = uh.p[r];                                           \
                accR[q][r] = FDOT2(hp, wR[r], accR[q][r]);                    \
                accI[q][r] = FDOT2(hp, wI[r], accI[q][r]);                    \
            }                                                                 \
        } } }

    FC_J(0)
    FC_J(1)
    FC_J(2)
#undef FC_J

    // ---- stage B: fc bias + act -> s_t2h, one b128 write per q ----
    {
        float4 fb01 = *(const float4*)(ws + FCB_OFF + cg*8);
        float4 fb23 = *(const float4*)(ws + FCB_OFF + cg*8 + 16);
        float fbm[4] = {fb01.x, fb01.z, fb23.x, fb23.z};
        float fbp[4] = {fb01.y, fb01.w, fb23.y, fb23.w};
#pragma unroll
        for (int q = 0; q < 4; ++q) {
            int tp = ntBase*16 + q*16 + col;
            bool pad = (t0 + tp >= TLEN);
            f16x8 v;
#pragma unroll
            for (int r = 0; r < 4; ++r) {
                float tr = ftanh(accR[q][r] + fbm[r]);
                float ti = fmaxf(accI[q][r] + fbp[r], 0.f);
                v[2*r]   = (_Float16)tr;
                v[2*r+1] = (_Float16)ti;
            }
            if (pad) v = (f16x8){0,0,0,0,0,0,0,0};
            int addr = (tp*128 + cg*4) ^ ((tp & 7) << 4);
            *(f16x8*)&s_t2h[addr] = v;
        }
    }

    // ---- stage C A fragments: 10 x 16B loads ----
    f16x8 afr[10];
    {
        int base = ((f*16 + col)*4 + g)*10;
#pragma unroll
        for (int kk = 0; kk < 10; ++kk) afr[kk] = tcp[base + kk];
    }
    __syncthreads();   // s_t2h ready (incl. zeroed tail rows)

    // ---- stage C (tc) MFMA ----
    {
        const int tb0 = w * 32, tb1 = tb0 + 16;
        f32x4 acc0 = {0,0,0,0}, acc1 = {0,0,0,0};
#pragma unroll
        for (int kt = 0; kt < 5; ++kt) {
#pragma unroll
            for (int kc = 0; kc < 2; ++kc) {
                f16x8 b0 = *(const f16x8*)&s_t2h[t2r_off(tb0 + col + 2*kt, kc, g)];
                f16x8 b1 = *(const f16x8*)&s_t2h[t2r_off(tb1 + col + 2*kt, kc, g)];
                acc0 = __builtin_amdgcn_mfma_f32_16x16x32_f16(afr[kt*2+kc], b0, acc0, 0, 0, 0);
                acc1 = __builtin_amdgcn_mfma_f32_16x16x32_f16(afr[kt*2+kc], b1, acc1, 0, 0, 0);
            }
        }
        float4 tcb = tb4[f*4 + g];
        float tcbv[4] = {tcb.x, tcb.y, tcb.z, tcb.w};
#pragma unroll
        for (int r = 0; r < 4; ++r) {
            int mm = g*4 + r;
            s_y[tb0 + col][mm] = acc0[r] + tcbv[r];
            s_y[tb1 + col][mm] = acc1[r] + tcbv[r];
        }
    }
    __syncthreads();   // s_y ready; s_t2h reads done -> s_e overlay usable

    // ---- act + cExp -> s_e (f16, padded rows SES=24 halves) ----
#pragma unroll
    for (int it = 0; it < 4; ++it) {
        int i  = it*256 + tid;
        int co = i >> 7, tl = i & 127;
        float yR = s_y[tl][co];
        float yI = s_y[tl][co + 8];
        float mg = __expf(ftanh(yR));
        float ph = fmaxf(yI, 0.f);
        float sn, cs;
        __sincosf(ph, &sn, &cs);
        *(f16x2*)&s_e[tl*SES + co*2] = (f16x2){(_Float16)(mg * cs), (_Float16)(mg * sn)};
    }
    __syncthreads();

    // ---- stage D (last) via MFMA ----
    {
        f16x8 dA = lap[(f*16 + col)*4 + g];
        float4 lb = lb4[f*4 + g];
        float lbv[4] = {lb.x, lb.y, lb.z, lb.w};
        float* obase = out + (size_t)b*4096000 + (size_t)f*TLEN + t0;
        int ooff[4];
#pragma unroll
        for (int r = 0; r < 4; ++r) {
            int m = g*4 + r;
            ooff[r] = (m >> 3)*2048000 + (m & 7)*256000;
        }
#pragma unroll
        for (int t2 = 0; t2 < 2; ++t2) {
            int tp = (w*2 + t2)*16 + col;
            // g>=2 MUST read zeros: junk could be NaN and 0*NaN = NaN in MFMA
            f16x8 eB = (g < 2) ? *(const f16x8*)&s_e[tp*SES + g*8]
                               : (f16x8){0,0,0,0,0,0,0,0};
            f32x4 o = __builtin_amdgcn_mfma_f32_16x16x32_f16(dA, eB, (f32x4){0,0,0,0}, 0, 0, 0);
            if (tp < TT && t0 + tp < TLEN) {
#pragma unroll
                for (int r = 0; r < 4; ++r)
                    obase[ooff[r] + tp] = o[r] + lbv[r];
            }
        }
    }
}

// ---------------- fallback (R7-style fused kernel, used if ws too small) ----------------
__device__ __forceinline__ int t2_off_fb(int tl, int p, int c) {
    int byte = tl * 128 + p * 64 + c * 2;
    byte ^= (tl & 7) << 4;
    return byte >> 1;
}

__global__ __launch_bounds__(256, 4) void mb_fused_fb(
    const float* __restrict__ x,
    const float* __restrict__ cswr, const float* __restrict__ cswi,
    const float* __restrict__ csbr, const float* __restrict__ csbi,
    const float* __restrict__ fcwr, const float* __restrict__ fcwi,
    const float* __restrict__ fcbr, const float* __restrict__ fcbi,
    const float* __restrict__ tcwr, const float* __restrict__ tcwi,
    const float* __restrict__ tcbr, const float* __restrict__ tcbi,
    const float* __restrict__ lawr, const float* __restrict__ lawi,
    const float* __restrict__ labr, const float* __restrict__ labi,
    float* __restrict__ out)
{
    const int tid  = threadIdx.x;
    const int tb   = blockIdx.x;
    const int f    = blockIdx.y;
    const int b    = blockIdx.z;
    const int t0   = tb * TT;
    const int lane = tid & 63;
    const int w    = tid >> 6;
    const int col  = lane & 15;
    const int g    = lane >> 4;

    __shared__ __align__(16) _Float16 s_t2h[T2R * 2 * CMID];
    __shared__ __align__(16) unsigned char s_u[THA * SLS];
    float (*s_y)[17] = (float (*)[17])s_u;

    for (int r = tid; r < THA; r += 256) {
        unsigned int* p = (unsigned int*)(s_u + r * SLS + 32);
        p[0] = 0x00003C00u;
#pragma unroll
        for (int q = 1; q < 8; ++q) p[q] = 0u;
    }
    ((unsigned int*)s_t2h)[THA*32 + tid] = 0u;

    const int cBase  = (w & 1) * 16;
    const int ntBase = (w >> 1) * 4;
    f32x4 accR[4], accI[4];
#pragma unroll
    for (int q = 0; q < 4; ++q) { accR[q] = (f32x4){0,0,0,0}; accI[q] = (f32x4){0,0,0,0}; }

    for (int j = 0; j < 3; ++j) {
        const int fp = f - 1 + j;
        if (fp < 0 || fp >= NF) continue;
        __syncthreads();
        const float* xr_base = x + ((size_t)(b*2+0)*CIN)*NF*TLEN + (size_t)fp*TLEN;
        const float* xi_base = x + ((size_t)(b*2+1)*CIN)*NF*TLEN + (size_t)fp*TLEN;
#pragma unroll
        for (int it = 0; it < 4; ++it) {
            int i  = it*256 + tid;
            int tl = i & 127, ci = i >> 7;
            int tg = t0 + tl;
            float lr = 0.f, li = 0.f;
            if (tg < TLEN) {
                float vr = xr_base[(size_t)ci*NF*TLEN + tg];
                float vi = xi_base[(size_t)ci*NF*TLEN + tg];
                lr = __logf(sqrtf(fmaf(vr, vr, vi*vi)) + 1e-6f);
                li = fatan2(vi, vr);
            }
            *(f16x2*)(s_u + tl*SLS + ci*4) = (f16x2){(_Float16)lr, (_Float16)li};
        }
        __syncthreads();
        const int ca = cBase + col;
        const float4 wrv = *(const float4*)(cswr + ((size_t)fp*CMID + ca)*CIN + (g & 1)*4);
        const float4 wiv = *(const float4*)(cswi + ((size_t)fp*CMID + ca)*CIN + (g & 1)*4);
        const float bR = csbr[fp*CMID + ca], bI = csbi[fp*CMID + ca];
        f16x8 aRe, aIm;
        if (g < 2) {
            aRe = (f16x8){(_Float16)wrv.x, (_Float16)(-wiv.x), (_Float16)wrv.y, (_Float16)(-wiv.y),
                          (_Float16)wrv.z, (_Float16)(-wiv.z), (_Float16)wrv.w, (_Float16)(-wiv.w)};
            aIm = (f16x8){(_Float16)wiv.x, (_Float16)wrv.x, (_Float16)wiv.y, (_Float16)wrv.y,
                          (_Float16)wiv.z, (_Float16)wrv.z, (_Float16)wiv.w, (_Float16)wrv.w};
        } else if (g == 2) {
            aRe = (f16x8){(_Float16)(bR - bI), 0, 0, 0, 0, 0, 0, 0};
            aIm = (f16x8){(_Float16)(bR + bI), 0, 0, 0, 0, 0, 0, 0};
        } else {
            aRe = (f16x8){0,0,0,0,0,0,0,0};
            aIm = (f16x8){0,0,0,0,0,0,0,0};
        }
        float frj[4], fij[4];
#pragma unroll
        for (int r = 0; r < 4; ++r) {
            int c = cBase + g*4 + r;
            frj[r] = fcwr[c*3 + j];
            fij[r] = fcwi[c*3 + j];
        }
#pragma unroll
        for (int q = 0; q < 4; ++q) {
            int tp = (ntBase + q)*16 + col;
            const unsigned char* bp = s_u + tp*SLS + g*16;
            f16x4 blo = *(const f16x4*)bp;
            f16x4 bhi = *(const f16x4*)(bp + 8);
            f16x8 bf = __builtin_shufflevector(blo, bhi, 0, 1, 2, 3, 4, 5, 6, 7);
            f32x4 dRe = __builtin_amdgcn_mfma_f32_16x16x32_f16(aRe, bf, (f32x4){0,0,0,0}, 0, 0, 0);
            f32x4 dIm = __builtin_amdgcn_mfma_f32_16x16x32_f16(aIm, bf, (f32x4){0,0,0,0}, 0, 0, 0);
#pragma unroll
            for (int r = 0; r < 4; ++r) {
                float ar = ftanh(dRe[r]);
                float ai = fmaxf(dIm[r], 0.f);
                accR[q][r] = fmaf(frj[r], ar, fmaf(-fij[r], ai, accR[q][r]));
                accI[q][r] = fmaf(frj[r], ai, fmaf( fij[r], ar, accI[q][r]));
            }
        }
    }
    {
        float fbr[4], fbi[4];
#pragma unroll
        for (int r = 0; r < 4; ++r) {
            int c = cBase + g*4 + r;
            fbr[r] = fcbr[c]; fbi[r] = fcbi[c];
        }
#pragma unroll
        for (int q = 0; q < 4; ++q) {
            int tp = (ntBase + q)*16 + col;
            bool pad = (t0 + tp >= TLEN);
#pragma unroll
            for (int r = 0; r < 4; ++r) {
                int c = cBase + g*4 + r;
                float tr = ftanh(accR[q][r] + (fbr[r] - fbi[r]));
                float ti = fmaxf(accI[q][r] + (fbr[r] + fbi[r]), 0.f);
                if (pad) { tr = 0.f; ti = 0.f; }
                s_t2h[t2_off_fb(tp, 0, c)] = (_Float16)tr;
                s_t2h[t2_off_fb(tp, 1, c)] = (_Float16)ti;
            }
        }
    }
    f16x8 afr[10];
    {
        const bool isI = col >= 8;
        const int co = col & 7;
        const float* wrp = tcwr + (size_t)(f*CIN + co)*(CMID*TK) + g*(8*TK);
        const float* wip = tcwi + (size_t)(f*CIN + co)*(CMID*TK) + g*(8*TK);
#pragma unroll
        for (int q = 0; q < 10; ++q) {
            float4 a4 = *(const float4*)&wrp[q*4];
            float4 b4 = *(const float4*)&wip[q*4];
#pragma unroll
            for (int r = 0; r < 4; ++r) {
                const int idx = q*4 + r;
                const int jj  = idx / 5;
                const int kt  = idx % 5;
                float a  = (r==0)?a4.x:(r==1)?a4.y:(r==2)?a4.z:a4.w;
                float bv = (r==0)?b4.x:(r==1)?b4.y:(r==2)?b4.z:b4.w;
                afr[kt][jj]      = (_Float16)(isI ? bv : a);
                afr[kt + TK][jj] = (_Float16)(isI ? a : -bv);
            }
        }
    }
    __syncthreads();
    {
        const int tb0 = w * 32, tb1 = tb0 + 16;
        f32x4 acc0 = {0,0,0,0}, acc1 = {0,0,0,0};
#pragma unroll
        for (int kk = 0; kk < 10; ++kk) {
            int p  = (kk < 5) ? 0 : 1;
            int kt = (kk < 5) ? kk : kk - 5;
            f16x8 b0 = *(const f16x8*)&s_t2h[t2_off_fb(tb0 + col + 2*kt, p, g*8)];
            f16x8 b1 = *(const f16x8*)&s_t2h[t2_off_fb(tb1 + col + 2*kt, p, g*8)];
            acc0 = __builtin_amdgcn_mfma_f32_16x16x32_f16(afr[kk], b0, acc0, 0, 0, 0);
            acc1 = __builtin_amdgcn_mfma_f32_16x16x32_f16(afr[kk], b1, acc1, 0, 0, 0);
        }
#pragma unroll
        for (int r = 0; r < 4; ++r) {
            int mm = g*4 + r;
            int coo = mm & 7;
            float bRv = tcbr[f*CIN + coo], bIv = tcbi[f*CIN + coo];
            float bias = (mm >= 8) ? (bRv + bIv) : (bRv - bIv);
            s_y[tb0 + col][mm] = acc0[r] + bias;
            s_y[tb1 + col][mm] = acc1[r] + bias;
        }
    }
    __syncthreads();
#pragma unroll
    for (int it = 0; it < 4; ++it) {
        int i  = it*256 + tid;
        int co = i >> 7, tl = i & 127;
        float yR = s_y[tl][co];
        float yI = s_y[tl][co + 8];
        float mg = __expf(ftanh(yR));
        float ph = fmaxf(yI, 0.f);
        float sn, cs;
        __sincosf(ph, &sn, &cs);
        s_y[tl][co]     = mg * cs;
        s_y[tl][co + 8] = mg * sn;
    }
    __syncthreads();
#pragma unroll
    for (int it = 0; it < 4; ++it) {
        int i   = it*256 + tid;
        int tl2 = i & 127;
        int co2 = __builtin_amdgcn_readfirstlane(i >> 7);
        int tg  = t0 + tl2;
        if (tl2 < TT && tg < TLEN) {
            const float4* lr4 = (const float4*)(lawr + ((size_t)f*CIN + co2)*CIN);
            const float4* li4 = (const float4*)(lawi + ((size_t)f*CIN + co2)*CIN);
            float4 a0 = lr4[0], a1 = lr4[1];
            float4 b0 = li4[0], b1 = li4[1];
            float oR = 0.f, oI = 0.f;
#pragma unroll
            for (int co = 0; co < CIN; ++co) {
                float er = s_y[tl2][co];
                float ei = s_y[tl2][co + 8];
                float a  = (co < 4) ? ((co==0)?a0.x:(co==1)?a0.y:(co==2)?a0.z:a0.w)
                                    : ((co==4)?a1.x:(co==5)?a1.y:(co==6)?a1.z:a1.w);
                float bb = (co < 4) ? ((co==0)?b0.x:(co==1)?b0.y:(co==2)?b0.z:b0.w)
                                    : ((co==4)?b1.x:(co==5)?b1.y:(co==6)?b1.z:b1.w);
                oR = fmaf(a, er, fmaf(-bb, ei, oR));
                oI = fmaf(a, ei, fmaf( bb, er, oI));
            }
            float br = labr[f*CIN + co2], bi = labi[f*CIN + co2];
            oR += br - bi;
            oI += br + bi;
            out[((size_t)(b*2+0)*CIN + co2)*NF*TLEN + (size_t)f*TLEN + tg] = oR;
            out[((size_t)(b*2+1)*CIN + co2)*NF*TLEN + (size_t)f*TLEN + tg] = oI;
        }
    }
}

extern "C" void kernel_launch(void* const* d_in, const int* in_sizes, int n_in,
                              void* d_out, int out_size, void* d_ws, size_t ws_size,
                              hipStream_t stream) {
    const float* p[17];
    for (int i = 0; i < 17; ++i) p[i] = (const float*)d_in[i];

    if (ws_size >= WS_ONE) {
        unsigned char* ws = (unsigned char*)d_ws;
        mb_pack<<<dim3(897), 256, 0, stream>>>(
            p[1], p[2], p[3], p[4],
            p[5], p[6], p[7], p[8],
            p[9], p[10], p[11], p[12],
            p[13], p[14], p[15], p[16], ws);
        if (ws_size >= WS_ALL) {
            mb_t1<<<dim3(8, NF, 4), 256, 0, stream>>>(p[0], ws, 0, T1_BATCH);
            mb_main<<<dim3(2304, 1, 4), 256, 0, stream>>>(ws, (float*)d_out, 0, T1_BATCH);
        } else {
            for (int b = 0; b < 4; ++b) {
                mb_t1<<<dim3(8, NF, 1), 256, 0, stream>>>(p[0], ws, b, 0u);
                mb_main<<<dim3(2304, 1, 1), 256, 0, stream>>>(ws, (float*)d_out, b, 0u);
            }
        }
    } else {
        mb_fused_fb<<<dim3(9, NF, 4), 256, 0, stream>>>(
            p[0],
            p[1], p[2], p[3], p[4],
            p[5], p[6], p[7], p[8],
            p[9], p[10], p[11], p[12],
            p[13], p[14], p[15], p[16],
            (float*)d_out);
    }
}